// Round 11
// baseline (249.187 us; speedup 1.0000x reference)
//
#include <hip/hip_runtime.h>
#include <math.h>

#define BATCH 16
#define CH    512
#define NTOK  1024
#define CHW   (CH * NTOK)
#define EPSV  1e-5f

typedef __attribute__((ext_vector_type(8))) short bf16x8;
typedef __attribute__((ext_vector_type(4))) float f32x4;

__device__ __forceinline__ unsigned short f2bf(float f) {
    union { float f; unsigned u; } cv; cv.f = f;
    unsigned r = cv.u + 0x7FFFu + ((cv.u >> 16) & 1u);   // RNE
    return (unsigned short)(r >> 16);
}

// async global -> LDS, 16 bytes/lane; LDS dest = wave-uniform base + lane*16.
__device__ __forceinline__ void async16(const unsigned short* g, unsigned short* l) {
    __builtin_amdgcn_global_load_lds(
        (const __attribute__((address_space(1))) void*)g,
        (__attribute__((address_space(3))) void*)l,
        16, 0, 0);
}

// XOR-swizzled 1KB micro-tile (16 rows x 32 shorts): element (row, q16B) at slot
// row*4 + ((q ^ (row>>1)) & 3). Staging lane l covers (row=l>>2, q=(l&3)^((l>>3)&3));
// fragment read offset swz = ((quad ^ (r16>>1))&3)*8 -> 2 lanes/bank (free).

// ---------------- workspace layout (byte offsets) ----------------
static const size_t OFF_WQKV = 256;                        // 1536*512 bf16
static const size_t OFF_OW   = OFF_WQKV + 1572864;         // 512*512 bf16
static const size_t OFF_XNT  = OFF_OW   + 524288;          // B*N*C bf16 (xn token-major)
static const size_t OFF_QT   = OFF_XNT  + 16777216;        // B*N*C bf16
static const size_t OFF_KT   = OFF_QT   + 16777216;        // B*N*C bf16
static const size_t OFF_V    = OFF_KT   + 16777216;        // B*C*N bf16 (channel-major)
static const size_t OFF_OT   = OFF_V    + 16777216;        // B*N*C bf16

// ---------------- stats partials ----------------
__global__ __launch_bounds__(256) void k_stats_partial(const float* __restrict__ x, float* __restrict__ ws) {
    int blk   = blockIdx.x;
    int b     = blk >> 6;
    int chunk = blk & 63;
    const float4* xp = (const float4*)(x + (size_t)b * CHW + (size_t)chunk * 8192);
    int t = threadIdx.x;
    float s = 0.0f, ss = 0.0f;
#pragma unroll
    for (int j = 0; j < 8; j++) {
        float4 v = xp[t + j * 256];
        s  += v.x + v.y + v.z + v.w;
        ss += v.x * v.x + v.y * v.y + v.z * v.z + v.w * v.w;
    }
#pragma unroll
    for (int off = 32; off; off >>= 1) {
        s  += __shfl_xor(s, off, 64);
        ss += __shfl_xor(ss, off, 64);
    }
    __shared__ float ls[4], lss[4];
    int wave = t >> 6, lane = t & 63;
    if (lane == 0) { ls[wave] = s; lss[wave] = ss; }
    __syncthreads();
    if (t == 0) {
        atomicAdd(&ws[b], ls[0] + ls[1] + ls[2] + ls[3]);
        atomicAdd(&ws[16 + b], lss[0] + lss[1] + lss[2] + lss[3]);
    }
}

// ---------------- weights f32 -> bf16 + stats zeroing (fused) ----------------
__global__ __launch_bounds__(256) void k_cvt2(const float* __restrict__ wq, const float* __restrict__ wo,
                                              unsigned short* __restrict__ WQ, unsigned short* __restrict__ WO,
                                              float* __restrict__ stats) {
    if (blockIdx.x == 0 && threadIdx.x < 64) stats[threadIdx.x] = 0.0f;
    int i = blockIdx.x * 256 + threadIdx.x;
    const float* src; unsigned short* dst; int off;
    if (i < 196608) { src = wq; dst = WQ; off = i; }
    else            { src = wo; dst = WO; off = i - 196608; }
    float4 v = ((const float4*)src)[off];
    ushort4 o;
    o.x = f2bf(v.x); o.y = f2bf(v.y); o.z = f2bf(v.z); o.w = f2bf(v.w);
    ((ushort4*)dst)[off] = o;
}

// ---------------- normalize + transpose -> xn_t[b][n][c] bf16 (stats inline) ----------------
__global__ __launch_bounds__(256) void k_xnt(const float* __restrict__ x,
                                             const float* __restrict__ nw,
                                             const float* __restrict__ nb,
                                             const float* __restrict__ ws,
                                             unsigned short* __restrict__ xnt) {
    __shared__ float ls[64][65];
    int b  = blockIdx.z;
    int c0 = blockIdx.y * 64;
    int n0 = blockIdx.x * 64;
    const float inv = 1.0f / (float)CHW;
    float mean = ws[b] * inv;
    float rstd = rsqrtf(ws[16 + b] * inv - mean * mean + EPSV);
    int t = threadIdx.x;
    int cl = t >> 4, n4 = t & 15;
    const float* xb = x + (size_t)b * CHW;
#pragma unroll
    for (int i = 0; i < 4; i++) {
        int c = c0 + cl + i * 16;
        float a  = rstd * nw[c];
        float bb = nb[c] - mean * a;
        float4 v = *(const float4*)(xb + (size_t)c * NTOK + n0 + n4 * 4);
        ls[cl + i * 16][n4 * 4 + 0] = v.x * a + bb;
        ls[cl + i * 16][n4 * 4 + 1] = v.y * a + bb;
        ls[cl + i * 16][n4 * 4 + 2] = v.z * a + bb;
        ls[cl + i * 16][n4 * 4 + 3] = v.w * a + bb;
    }
    __syncthreads();
    int nl = t >> 4, c4 = t & 15;
    unsigned short* dst = xnt + (size_t)b * NTOK * CH;
#pragma unroll
    for (int i = 0; i < 4; i++) {
        int n = n0 + nl + i * 16;
        ushort4 o;
        o.x = f2bf(ls[c4 * 4 + 0][nl + i * 16]);
        o.y = f2bf(ls[c4 * 4 + 1][nl + i * 16]);
        o.z = f2bf(ls[c4 * 4 + 2][nl + i * 16]);
        o.w = f2bf(ls[c4 * 4 + 3][nl + i * 16]);
        *(ushort4*)(dst + (size_t)n * CH + c0 + c4 * 4) = o;
    }
}

// ---------------- MFMA GEMM core: 128(M) x 256(N), swizzled LDS ----------------
__device__ __forceinline__ void mfma_core2(const unsigned short* __restrict__ A, int lda,
                                           const unsigned short* __restrict__ B, int ldb,
                                           int K, int m0, int n0,
                                           unsigned short* sm,
                                           f32x4 acc[4][8]) {
    const int t = threadIdx.x;
    const int w = t >> 6, lane = t & 63;
    const int wm = (w & 1) * 64, wn = (w >> 1) * 128;
    const int r16 = lane & 15, quad = lane >> 4;
#pragma unroll
    for (int i = 0; i < 4; i++)
#pragma unroll
        for (int j = 0; j < 8; j++) acc[i][j] = (f32x4){0.f, 0.f, 0.f, 0.f};
    const int sr = lane >> 2;
    const int sk = (((lane & 3) ^ ((lane >> 3) & 3))) * 8;
    const int swz = ((quad ^ (r16 >> 1)) & 3) * 8;
    const unsigned short* gA0 = A + (size_t)(m0 + w * 32 + sr) * lda + sk;
    const unsigned short* gA1 = gA0 + (size_t)16 * lda;
    const unsigned short* gB0 = B + (size_t)(n0 + w * 64 + sr) * ldb + sk;
    const unsigned short* gB1 = gB0 + (size_t)16 * ldb;
    const unsigned short* gB2 = gB0 + (size_t)32 * ldb;
    const unsigned short* gB3 = gB0 + (size_t)48 * ldb;
    unsigned short* lA0 = sm + (w * 32) * 32;
    unsigned short* lA1 = sm + (w * 32 + 16) * 32;
    unsigned short* lB0 = sm + 8192 + (w * 64) * 32;
    unsigned short* lB1 = lB0 + 16 * 32;
    unsigned short* lB2 = lB0 + 32 * 32;
    unsigned short* lB3 = lB0 + 48 * 32;
    const int T = K >> 5;
    async16(gA0, lA0); async16(gA1, lA1);
    async16(gB0, lB0); async16(gB1, lB1); async16(gB2, lB2); async16(gB3, lB3);
    for (int tt = 0; tt < T; tt++) {
        __syncthreads();
        const int ab = (tt & 1) << 12;
        const int bb = (tt & 1) << 13;
        if (tt + 1 < T) {
            const int nab = ab ^ 4096, nbb = bb ^ 8192;
            const int ko = (tt + 1) << 5;
            async16(gA0 + ko, lA0 + nab); async16(gA1 + ko, lA1 + nab);
            async16(gB0 + ko, lB0 + nbb); async16(gB1 + ko, lB1 + nbb);
            async16(gB2 + ko, lB2 + nbb); async16(gB3 + ko, lB3 + nbb);
        }
        bf16x8 af[4], bfr[8];
#pragma unroll
        for (int i = 0; i < 4; i++) af[i]  = *(const bf16x8*)(sm + ab + (wm + i * 16 + r16) * 32 + swz);
#pragma unroll
        for (int j = 0; j < 8; j++) bfr[j] = *(const bf16x8*)(sm + 8192 + bb + (wn + j * 16 + r16) * 32 + swz);
#pragma unroll
        for (int i = 0; i < 4; i++)
#pragma unroll
            for (int j = 0; j < 8; j++)
                acc[i][j] = __builtin_amdgcn_mfma_f32_16x16x32_bf16(af[i], bfr[j], acc[i][j], 0, 0, 0);
    }
}

#define TS1 136
#define TS2 264

// ---------------- GEMM1: qkv ----------------
__global__ __launch_bounds__(256, 2) void k_gemm_qkv(const unsigned short* __restrict__ Wq,
                                                     const float* __restrict__ qb,
                                                     const unsigned short* __restrict__ XNT,
                                                     unsigned short* __restrict__ QT,
                                                     unsigned short* __restrict__ KT,
                                                     unsigned short* __restrict__ V) {
    __shared__ __align__(16) unsigned short smem[256 * TS1];
    const int b  = blockIdx.z;
    const int m0 = blockIdx.y * 128;
    const int n0 = blockIdx.x * 256;
    f32x4 acc[4][8];
    mfma_core2(Wq, CH, XNT + (size_t)b * NTOK * CH, CH, CH, m0, n0, smem, acc);
    const int t = threadIdx.x;
    const int w = t >> 6, lane = t & 63;
    const int wm = (w & 1) * 64, wn = (w >> 1) * 128;
    const int r16 = lane & 15, quad = lane >> 4;
    const int region = m0 >> 9;
    __syncthreads();
    if (region < 2) {
#pragma unroll
        for (int i = 0; i < 4; i++) {
            const int ol = wm + i * 16 + quad * 4;
            const int og = m0 + ol;
            const float b0 = qb[og], b1 = qb[og + 1], b2 = qb[og + 2], b3 = qb[og + 3];
#pragma unroll
            for (int j = 0; j < 8; j++) {
                const int nl = wn + j * 16 + r16;
                f32x4 a = acc[i][j];
                ushort4 pk;
                pk.x = f2bf(a[0] + b0); pk.y = f2bf(a[1] + b1);
                pk.z = f2bf(a[2] + b2); pk.w = f2bf(a[3] + b3);
                *(ushort4*)(smem + nl * TS1 + ol) = pk;
            }
        }
        __syncthreads();
        unsigned short* dst = ((region == 0) ? QT : KT) + (size_t)b * NTOK * CH + (size_t)n0 * CH + (m0 & 511);
#pragma unroll
        for (int p = 0; p < 32; p++) {
            const int row = (t >> 5) + p * 8;
            const int seg = (t & 31) * 4;
            *(ushort4*)(dst + (size_t)row * CH + seg) = *(const ushort4*)(smem + row * TS1 + seg);
        }
    } else {
#pragma unroll
        for (int i = 0; i < 4; i++) {
            const int ol = wm + i * 16 + quad * 4;
            const int og = m0 + ol;
#pragma unroll
            for (int j = 0; j < 8; j++) {
                const int nl = wn + j * 16 + r16;
                f32x4 a = acc[i][j];
#pragma unroll
                for (int r = 0; r < 4; r++)
                    smem[(ol + r) * TS2 + nl] = f2bf(a[r] + qb[og + r]);
            }
        }
        __syncthreads();
        unsigned short* dst = V + (size_t)b * CH * NTOK + (size_t)(m0 & 511) * NTOK + n0;
#pragma unroll
        for (int p = 0; p < 32; p++) {
            const int row = (t >> 5) + (p & 15) * 8;
            const int seg = (t & 31) * 4 + (p >> 4) * 128;
            *(ushort4*)(dst + (size_t)row * NTOK + seg) = *(const ushort4*)(smem + row * TS2 + seg);
        }
    }
}

// ---------------- fused flash attention v6: v5 algorithm, VGPR cap lifted ----------
// __launch_bounds__(512, 1): 8-wave block = 2 waves/SIMD naturally; budget 512 VGPR,
// actual need ~230 (qf 128 + accO 64 + pf/vf/addr) -> 2 waves/SIMD at runtime, NO spill.
// Wave (qg = w&1, h = w>>1) computes S[32q][16keys] sharing each kf read across two
// q-subtiles (halves S-phase K-read redundancy vs R9). PV: wave owns 64 channels.
// LDS shorts: smK [0,32768); smV [32768,65536); smP [65536,69888) = [64 q][68];
// lsum quarters (4x64 f32) at [69888,70400). 140800 B -> 1 block/CU.
__global__ __launch_bounds__(512, 1) void k_attn(const unsigned short* __restrict__ QT,
                                                 const unsigned short* __restrict__ KTg,
                                                 const unsigned short* __restrict__ Vg,
                                                 unsigned short* __restrict__ OT) {
    __shared__ __align__(16) unsigned short sm[70400];
    unsigned short* smK = sm;
    unsigned short* smV = sm + 32768;
    unsigned short* smP = sm + 65536;
    float* lsum2 = (float*)(sm + 69888);

    const int bid = blockIdx.x;
    const int xcd = bid & 7, slot = bid >> 3;
    const int b   = xcd * 2 + (slot & 1);   // 2 batches per XCD (K/V L2-resident)
    const int q0  = (slot >> 1) * 64;

    const int t = threadIdx.x;
    const int w = t >> 6, lane = t & 63;
    const int qg = w & 1, h = w >> 1;       // qg: 32-q group; h: 16-key quarter
    const int r16 = lane & 15, quad = lane >> 4;
    const int srow = lane >> 2;
    const int sc   = (((lane & 3) ^ ((lane >> 3) & 3))) * 8;
    const int swz  = ((quad ^ (r16 >> 1)) & 3) * 8;

    const unsigned short* Qb = QT  + (size_t)b * NTOK * CH;
    const unsigned short* Kb = KTg + (size_t)b * NTOK * CH;
    const unsigned short* Vb = Vg  + (size_t)b * CH * NTOK;

    // Q fragments: wave owns q-rows q0 + qg*32 + {0,16} + r16
    bf16x8 qf[2][16];
    {
        const unsigned short* qrow0 = Qb + (size_t)(q0 + qg * 32 + r16) * CH + quad * 8;
        const unsigned short* qrow1 = qrow0 + (size_t)16 * CH;
#pragma unroll
        for (int kc = 0; kc < 16; kc++) {
            qf[0][kc] = *(const bf16x8*)(qrow0 + kc * 32);
            qf[1][kc] = *(const bf16x8*)(qrow1 + kc * 32);
        }
    }

    f32x4 accO[16];   // [qj 0..3][cj 0..3]: O[64 q][channels w*64 .. +63]
#pragma unroll
    for (int j = 0; j < 16; j++) accO[j] = (f32x4){0.f, 0.f, 0.f, 0.f};
    float lsum[2][4] = {{0.f, 0.f, 0.f, 0.f}, {0.f, 0.f, 0.f, 0.f}};
    const float scale = 0.044194173824159216f;  // 512^-0.5

    // prologue: stage K(0); wave stages chunks w*8 .. w*8+7 (chunk = keygroup*16 + kc)
#pragma unroll
    for (int i = 0; i < 8; i++) {
        const int ch = w * 8 + i, g = ch >> 4, kc = ch & 15;
        async16(Kb + (size_t)(g * 16 + srow) * CH + kc * 32 + sc, smK + ch * 512);
    }
    __syncthreads();

    for (int kt = 0; kt < 16; kt++) {
        // stage V(kt): wave stages channel groups w*4 .. w*4+3 (8 asyncs)
        {
            const unsigned short* vbase = Vb + (size_t)kt * 64;
#pragma unroll
            for (int cgi = 0; cgi < 4; cgi++) {
                const int cg = w * 4 + cgi;
#pragma unroll
                for (int kk = 0; kk < 2; kk++)
                    async16(vbase + (size_t)(cg * 16 + srow) * NTOK + kk * 32 + sc,
                            smV + (cg * 2 + kk) * 512);
            }
        }
        // S = Q·K^T : wave computes S[32q(qg)][16 keys (h)], kf shared by both q-subtiles
        f32x4 accS[2];
        accS[0] = (f32x4){0.f, 0.f, 0.f, 0.f};
        accS[1] = (f32x4){0.f, 0.f, 0.f, 0.f};
#pragma unroll
        for (int kc = 0; kc < 16; kc++) {
            bf16x8 kf = *(const bf16x8*)(smK + (h * 16 + kc) * 512 + r16 * 32 + swz);
            accS[0] = __builtin_amdgcn_mfma_f32_16x16x32_bf16(qf[0][kc], kf, accS[0], 0, 0, 0);
            accS[1] = __builtin_amdgcn_mfma_f32_16x16x32_bf16(qf[1][kc], kf, accS[1], 0, 0, 0);
        }
        // exp + P write (rows qg*32+qs*16+quad*4+r, cols h*16+r16)
#pragma unroll
        for (int qs = 0; qs < 2; qs++) {
#pragma unroll
            for (int r = 0; r < 4; r++) {
                float e = __expf(accS[qs][r] * scale);
                lsum[qs][r] += e;
                smP[(qg * 32 + qs * 16 + quad * 4 + r) * 68 + h * 16 + r16] = f2bf(e);
            }
        }
        __syncthreads();   // drains V(kt); P visible; smK free
        // stage K(kt+1)
        if (kt < 15) {
            const unsigned short* kbase = Kb + (size_t)(kt + 1) * 64 * CH;
#pragma unroll
            for (int i = 0; i < 8; i++) {
                const int ch = w * 8 + i, g = ch >> 4, kc = ch & 15;
                async16(kbase + (size_t)(g * 16 + srow) * CH + kc * 32 + sc, smK + ch * 512);
            }
        }
        // P frags: all 64 q rows
        bf16x8 pf[4][2];
#pragma unroll
        for (int qj = 0; qj < 4; qj++)
#pragma unroll
            for (int kk = 0; kk < 2; kk++)
                pf[qj][kk] = *(const bf16x8*)(smP + (qj * 16 + r16) * 68 + kk * 32 + quad * 8);
        // PV: wave accumulates O[64 q][channels w*64 .. +63]
#pragma unroll
        for (int cj = 0; cj < 4; cj++) {
            bf16x8 vf0 = *(const bf16x8*)(smV + ((w * 4 + cj) * 2 + 0) * 512 + r16 * 32 + swz);
            bf16x8 vf1 = *(const bf16x8*)(smV + ((w * 4 + cj) * 2 + 1) * 512 + r16 * 32 + swz);
#pragma unroll
            for (int qj = 0; qj < 4; qj++) {
                accO[qj * 4 + cj] = __builtin_amdgcn_mfma_f32_16x16x32_bf16(pf[qj][0], vf0, accO[qj * 4 + cj], 0, 0, 0);
                accO[qj * 4 + cj] = __builtin_amdgcn_mfma_f32_16x16x32_bf16(pf[qj][1], vf1, accO[qj * 4 + cj], 0, 0, 0);
            }
        }
        __syncthreads();   // drains K(kt+1); smV/smP free
    }

    // publish per-quarter row-sum partials (reduce across 16 key-lanes)
#pragma unroll
    for (int qs = 0; qs < 2; qs++)
#pragma unroll
        for (int r = 0; r < 4; r++) {
            float v = lsum[qs][r];
            v += __shfl_xor(v, 1, 64);
            v += __shfl_xor(v, 2, 64);
            v += __shfl_xor(v, 4, 64);
            v += __shfl_xor(v, 8, 64);
            if (r16 == 0) lsum2[h * 64 + qg * 32 + qs * 16 + quad * 4 + r] = v;
        }
    __syncthreads();
    // normalize + transpose tile [64 q][512 c] (stride 520)
#pragma unroll
    for (int qj = 0; qj < 4; qj++) {
        float iv[4];
#pragma unroll
        for (int r = 0; r < 4; r++) {
            const int row = qj * 16 + quad * 4 + r;
            iv[r] = 1.0f / (lsum2[row] + lsum2[64 + row] + lsum2[128 + row] + lsum2[192 + row]);
        }
#pragma unroll
        for (int cj = 0; cj < 4; cj++) {
            f32x4 a = accO[qj * 4 + cj];
#pragma unroll
            for (int r = 0; r < 4; r++)
                sm[(qj * 16 + quad * 4 + r) * 520 + w * 64 + cj * 16 + r16] = f2bf(a[r] * iv[r]);
        }
    }
    __syncthreads();
    unsigned short* dst = OT + (size_t)b * NTOK * CH + (size_t)q0 * CH;
#pragma unroll
    for (int p = 0; p < 16; p++) {
        const int row = (t >> 7) + p * 4;
        const int seg = (t & 127) * 4;
        *(ushort4*)(dst + (size_t)row * CH + seg) = *(const ushort4*)(sm + row * 520 + seg);
    }
}

// ---------------- GEMM4: out = OW·O + ob + x ----------------
__global__ __launch_bounds__(256, 2) void k_gemm_out(const unsigned short* __restrict__ OW,
                                                     const float* __restrict__ ob,
                                                     const unsigned short* __restrict__ OT,
                                                     const float* __restrict__ x,
                                                     float* __restrict__ out) {
    __shared__ __align__(16) unsigned short smem[24576];
    const int b  = blockIdx.z;
    const int m0 = blockIdx.y * 128;
    const int n0 = blockIdx.x * 256;
    f32x4 acc[4][8];
    mfma_core2(OW, CH, OT + (size_t)b * NTOK * CH, CH, CH, m0, n0, smem, acc);
    const int t = threadIdx.x;
    const int w = t >> 6, lane = t & 63;
    const int wm = (w & 1) * 64, wn = (w >> 1) * 128;
    const int r16 = lane & 15, quad = lane >> 4;
#pragma unroll
    for (int i = 0; i < 4; i++) {
        const int o0g = m0 + wm + i * 16 + quad * 4;
#pragma unroll
        for (int j = 0; j < 8; j++) {
            const int col = n0 + wn + j * 16 + r16;
            f32x4 a = acc[i][j];
#pragma unroll
            for (int r = 0; r < 4; r++) {
                size_t idx = (size_t)b * CHW + (size_t)(o0g + r) * NTOK + col;
                out[idx] = a[r] + ob[o0g + r] + x[idx];
            }
        }
    }
}

extern "C" void kernel_launch(void* const* d_in, const int* in_sizes, int n_in,
                              void* d_out, int out_size, void* d_ws, size_t ws_size,
                              hipStream_t stream) {
    const float* x      = (const float*)d_in[0];
    const float* norm_w = (const float*)d_in[1];
    const float* norm_b = (const float*)d_in[2];
    const float* qkv_w  = (const float*)d_in[3];
    const float* qkv_b  = (const float*)d_in[4];
    const float* out_w  = (const float*)d_in[5];
    const float* out_b  = (const float*)d_in[6];
    float* out = (float*)d_out;
    char* wsb  = (char*)d_ws;

    float* stats = (float*)wsb;
    unsigned short* WQ  = (unsigned short*)(wsb + OFF_WQKV);
    unsigned short* OW  = (unsigned short*)(wsb + OFF_OW);
    unsigned short* XNT = (unsigned short*)(wsb + OFF_XNT);
    unsigned short* QT  = (unsigned short*)(wsb + OFF_QT);
    unsigned short* KT  = (unsigned short*)(wsb + OFF_KT);
    unsigned short* V   = (unsigned short*)(wsb + OFF_V);
    unsigned short* OT  = (unsigned short*)(wsb + OFF_OT);

    k_cvt2<<<1024, 256, 0, stream>>>(qkv_w, out_w, WQ, OW, stats);
    k_stats_partial<<<BATCH * 64, 256, 0, stream>>>(x, stats);
    k_xnt<<<dim3(NTOK / 64, CH / 64, BATCH), 256, 0, stream>>>(x, norm_w, norm_b, stats, XNT);
    k_gemm_qkv<<<dim3(NTOK / 256, 3 * CH / 128, BATCH), 256, 0, stream>>>(WQ, qkv_b, XNT, QT, KT, V);
    k_attn<<<256, 512, 0, stream>>>(QT, KT, V, OT);
    k_gemm_out<<<dim3(NTOK / 256, CH / 128, BATCH), 256, 0, stream>>>(OW, out_b, OT, x, out);
}

// Round 12
// 228.301 us; speedup vs baseline: 1.0915x; 1.0915x over previous
//
#include <hip/hip_runtime.h>
#include <math.h>

#define BATCH 16
#define CH    512
#define NTOK  1024
#define CHW   (CH * NTOK)
#define EPSV  1e-5f

typedef __attribute__((ext_vector_type(8))) short bf16x8;
typedef __attribute__((ext_vector_type(4))) float f32x4;

__device__ __forceinline__ unsigned short f2bf(float f) {
    union { float f; unsigned u; } cv; cv.f = f;
    unsigned r = cv.u + 0x7FFFu + ((cv.u >> 16) & 1u);   // RNE
    return (unsigned short)(r >> 16);
}

// async global -> LDS, 16 bytes/lane; LDS dest = wave-uniform base + lane*16.
__device__ __forceinline__ void async16(const unsigned short* g, unsigned short* l) {
    __builtin_amdgcn_global_load_lds(
        (const __attribute__((address_space(1))) void*)g,
        (__attribute__((address_space(3))) void*)l,
        16, 0, 0);
}

// XOR-swizzled 1KB micro-tile (16 rows x 32 shorts): element (row, q16B) at slot
// row*4 + ((q ^ (row>>1)) & 3). Staging lane l covers (row=l>>2, q=(l&3)^((l>>3)&3));
// fragment read offset swz = ((quad ^ (r16>>1))&3)*8 -> 2 lanes/bank (free).

// ---------------- workspace layout (byte offsets) ----------------
static const size_t OFF_WQKV = 256;                        // 1536*512 bf16
static const size_t OFF_OW   = OFF_WQKV + 1572864;         // 512*512 bf16
static const size_t OFF_XNT  = OFF_OW   + 524288;          // B*N*C bf16 (xn token-major)
static const size_t OFF_QT   = OFF_XNT  + 16777216;        // B*N*C bf16
static const size_t OFF_KT   = OFF_QT   + 16777216;        // B*N*C bf16
static const size_t OFF_V    = OFF_KT   + 16777216;        // B*C*N bf16 (channel-major)
static const size_t OFF_OT   = OFF_V    + 16777216;        // B*N*C bf16

// ---------------- stats partials ----------------
__global__ __launch_bounds__(256) void k_stats_partial(const float* __restrict__ x, float* __restrict__ ws) {
    int blk   = blockIdx.x;
    int b     = blk >> 6;
    int chunk = blk & 63;
    const float4* xp = (const float4*)(x + (size_t)b * CHW + (size_t)chunk * 8192);
    int t = threadIdx.x;
    float s = 0.0f, ss = 0.0f;
#pragma unroll
    for (int j = 0; j < 8; j++) {
        float4 v = xp[t + j * 256];
        s  += v.x + v.y + v.z + v.w;
        ss += v.x * v.x + v.y * v.y + v.z * v.z + v.w * v.w;
    }
#pragma unroll
    for (int off = 32; off; off >>= 1) {
        s  += __shfl_xor(s, off, 64);
        ss += __shfl_xor(ss, off, 64);
    }
    __shared__ float ls[4], lss[4];
    int wave = t >> 6, lane = t & 63;
    if (lane == 0) { ls[wave] = s; lss[wave] = ss; }
    __syncthreads();
    if (t == 0) {
        atomicAdd(&ws[b], ls[0] + ls[1] + ls[2] + ls[3]);
        atomicAdd(&ws[16 + b], lss[0] + lss[1] + lss[2] + lss[3]);
    }
}

// ---------------- weights f32 -> bf16 + stats zeroing (fused) ----------------
__global__ __launch_bounds__(256) void k_cvt2(const float* __restrict__ wq, const float* __restrict__ wo,
                                              unsigned short* __restrict__ WQ, unsigned short* __restrict__ WO,
                                              float* __restrict__ stats) {
    if (blockIdx.x == 0 && threadIdx.x < 64) stats[threadIdx.x] = 0.0f;
    int i = blockIdx.x * 256 + threadIdx.x;
    const float* src; unsigned short* dst; int off;
    if (i < 196608) { src = wq; dst = WQ; off = i; }
    else            { src = wo; dst = WO; off = i - 196608; }
    float4 v = ((const float4*)src)[off];
    ushort4 o;
    o.x = f2bf(v.x); o.y = f2bf(v.y); o.z = f2bf(v.z); o.w = f2bf(v.w);
    ((ushort4*)dst)[off] = o;
}

// ---------------- normalize + transpose -> xn_t[b][n][c] bf16 (stats inline) ----------------
__global__ __launch_bounds__(256) void k_xnt(const float* __restrict__ x,
                                             const float* __restrict__ nw,
                                             const float* __restrict__ nb,
                                             const float* __restrict__ ws,
                                             unsigned short* __restrict__ xnt) {
    __shared__ float ls[64][65];
    int b  = blockIdx.z;
    int c0 = blockIdx.y * 64;
    int n0 = blockIdx.x * 64;
    const float inv = 1.0f / (float)CHW;
    float mean = ws[b] * inv;
    float rstd = rsqrtf(ws[16 + b] * inv - mean * mean + EPSV);
    int t = threadIdx.x;
    int cl = t >> 4, n4 = t & 15;
    const float* xb = x + (size_t)b * CHW;
#pragma unroll
    for (int i = 0; i < 4; i++) {
        int c = c0 + cl + i * 16;
        float a  = rstd * nw[c];
        float bb = nb[c] - mean * a;
        float4 v = *(const float4*)(xb + (size_t)c * NTOK + n0 + n4 * 4);
        ls[cl + i * 16][n4 * 4 + 0] = v.x * a + bb;
        ls[cl + i * 16][n4 * 4 + 1] = v.y * a + bb;
        ls[cl + i * 16][n4 * 4 + 2] = v.z * a + bb;
        ls[cl + i * 16][n4 * 4 + 3] = v.w * a + bb;
    }
    __syncthreads();
    int nl = t >> 4, c4 = t & 15;
    unsigned short* dst = xnt + (size_t)b * NTOK * CH;
#pragma unroll
    for (int i = 0; i < 4; i++) {
        int n = n0 + nl + i * 16;
        ushort4 o;
        o.x = f2bf(ls[c4 * 4 + 0][nl + i * 16]);
        o.y = f2bf(ls[c4 * 4 + 1][nl + i * 16]);
        o.z = f2bf(ls[c4 * 4 + 2][nl + i * 16]);
        o.w = f2bf(ls[c4 * 4 + 3][nl + i * 16]);
        *(ushort4*)(dst + (size_t)n * CH + c0 + c4 * 4) = o;
    }
}

// ---------------- MFMA GEMM core: 128(M) x 256(N), swizzled LDS ----------------
__device__ __forceinline__ void mfma_core2(const unsigned short* __restrict__ A, int lda,
                                           const unsigned short* __restrict__ B, int ldb,
                                           int K, int m0, int n0,
                                           unsigned short* sm,
                                           f32x4 acc[4][8]) {
    const int t = threadIdx.x;
    const int w = t >> 6, lane = t & 63;
    const int wm = (w & 1) * 64, wn = (w >> 1) * 128;
    const int r16 = lane & 15, quad = lane >> 4;
#pragma unroll
    for (int i = 0; i < 4; i++)
#pragma unroll
        for (int j = 0; j < 8; j++) acc[i][j] = (f32x4){0.f, 0.f, 0.f, 0.f};
    const int sr = lane >> 2;
    const int sk = (((lane & 3) ^ ((lane >> 3) & 3))) * 8;
    const int swz = ((quad ^ (r16 >> 1)) & 3) * 8;
    const unsigned short* gA0 = A + (size_t)(m0 + w * 32 + sr) * lda + sk;
    const unsigned short* gA1 = gA0 + (size_t)16 * lda;
    const unsigned short* gB0 = B + (size_t)(n0 + w * 64 + sr) * ldb + sk;
    const unsigned short* gB1 = gB0 + (size_t)16 * ldb;
    const unsigned short* gB2 = gB0 + (size_t)32 * ldb;
    const unsigned short* gB3 = gB0 + (size_t)48 * ldb;
    unsigned short* lA0 = sm + (w * 32) * 32;
    unsigned short* lA1 = sm + (w * 32 + 16) * 32;
    unsigned short* lB0 = sm + 8192 + (w * 64) * 32;
    unsigned short* lB1 = lB0 + 16 * 32;
    unsigned short* lB2 = lB0 + 32 * 32;
    unsigned short* lB3 = lB0 + 48 * 32;
    const int T = K >> 5;
    async16(gA0, lA0); async16(gA1, lA1);
    async16(gB0, lB0); async16(gB1, lB1); async16(gB2, lB2); async16(gB3, lB3);
    for (int tt = 0; tt < T; tt++) {
        __syncthreads();
        const int ab = (tt & 1) << 12;
        const int bb = (tt & 1) << 13;
        if (tt + 1 < T) {
            const int nab = ab ^ 4096, nbb = bb ^ 8192;
            const int ko = (tt + 1) << 5;
            async16(gA0 + ko, lA0 + nab); async16(gA1 + ko, lA1 + nab);
            async16(gB0 + ko, lB0 + nbb); async16(gB1 + ko, lB1 + nbb);
            async16(gB2 + ko, lB2 + nbb); async16(gB3 + ko, lB3 + nbb);
        }
        bf16x8 af[4], bfr[8];
#pragma unroll
        for (int i = 0; i < 4; i++) af[i]  = *(const bf16x8*)(sm + ab + (wm + i * 16 + r16) * 32 + swz);
#pragma unroll
        for (int j = 0; j < 8; j++) bfr[j] = *(const bf16x8*)(sm + 8192 + bb + (wn + j * 16 + r16) * 32 + swz);
#pragma unroll
        for (int i = 0; i < 4; i++)
#pragma unroll
            for (int j = 0; j < 8; j++)
                acc[i][j] = __builtin_amdgcn_mfma_f32_16x16x32_bf16(af[i], bfr[j], acc[i][j], 0, 0, 0);
    }
}

#define TS1 136
#define TS2 264

// ---------------- GEMM1: qkv ----------------
__global__ __launch_bounds__(256, 2) void k_gemm_qkv(const unsigned short* __restrict__ Wq,
                                                     const float* __restrict__ qb,
                                                     const unsigned short* __restrict__ XNT,
                                                     unsigned short* __restrict__ QT,
                                                     unsigned short* __restrict__ KT,
                                                     unsigned short* __restrict__ V) {
    __shared__ __align__(16) unsigned short smem[256 * TS1];
    const int b  = blockIdx.z;
    const int m0 = blockIdx.y * 128;
    const int n0 = blockIdx.x * 256;
    f32x4 acc[4][8];
    mfma_core2(Wq, CH, XNT + (size_t)b * NTOK * CH, CH, CH, m0, n0, smem, acc);
    const int t = threadIdx.x;
    const int w = t >> 6, lane = t & 63;
    const int wm = (w & 1) * 64, wn = (w >> 1) * 128;
    const int r16 = lane & 15, quad = lane >> 4;
    const int region = m0 >> 9;
    __syncthreads();
    if (region < 2) {
#pragma unroll
        for (int i = 0; i < 4; i++) {
            const int ol = wm + i * 16 + quad * 4;
            const int og = m0 + ol;
            const float b0 = qb[og], b1 = qb[og + 1], b2 = qb[og + 2], b3 = qb[og + 3];
#pragma unroll
            for (int j = 0; j < 8; j++) {
                const int nl = wn + j * 16 + r16;
                f32x4 a = acc[i][j];
                ushort4 pk;
                pk.x = f2bf(a[0] + b0); pk.y = f2bf(a[1] + b1);
                pk.z = f2bf(a[2] + b2); pk.w = f2bf(a[3] + b3);
                *(ushort4*)(smem + nl * TS1 + ol) = pk;
            }
        }
        __syncthreads();
        unsigned short* dst = ((region == 0) ? QT : KT) + (size_t)b * NTOK * CH + (size_t)n0 * CH + (m0 & 511);
#pragma unroll
        for (int p = 0; p < 32; p++) {
            const int row = (t >> 5) + p * 8;
            const int seg = (t & 31) * 4;
            *(ushort4*)(dst + (size_t)row * CH + seg) = *(const ushort4*)(smem + row * TS1 + seg);
        }
    } else {
#pragma unroll
        for (int i = 0; i < 4; i++) {
            const int ol = wm + i * 16 + quad * 4;
            const int og = m0 + ol;
#pragma unroll
            for (int j = 0; j < 8; j++) {
                const int nl = wn + j * 16 + r16;
                f32x4 a = acc[i][j];
#pragma unroll
                for (int r = 0; r < 4; r++)
                    smem[(ol + r) * TS2 + nl] = f2bf(a[r] + qb[og + r]);
            }
        }
        __syncthreads();
        unsigned short* dst = V + (size_t)b * CH * NTOK + (size_t)(m0 & 511) * NTOK + n0;
#pragma unroll
        for (int p = 0; p < 32; p++) {
            const int row = (t >> 5) + (p & 15) * 8;
            const int seg = (t & 31) * 4 + (p >> 4) * 128;
            *(ushort4*)(dst + (size_t)row * NTOK + seg) = *(const ushort4*)(smem + row * TS2 + seg);
        }
    }
}

// ---------------- fused flash attention v7: 256 thr, 32-q blocks, 2 blocks/CU ----
// Grid 512 = 16 batches x 32 q-tiles (32 rows). 4 waves. Key-tile 32, 32 tiles.
// S: wave (qg=w&1, kg=w>>1) computes S[16q][16k] (K redundancy 2x). PV: wave owns
// 128 channels, O[32q][128c] (V read exactly once). 2-barrier pipeline, swizzled.
// LDS shorts: smK [0,16384); smV [16384,32768); smP [32768,34048) = [32 q][40];
// lsum2 64 f32 at [34048,34176). Total 68352 B -> 2 blocks/CU (8 waves/CU).
#define PS 40   // smP row stride (80 B: 16B-aligned rows for b128 pf reads)
__global__ __launch_bounds__(256, 2) void k_attn(const unsigned short* __restrict__ QT,
                                                 const unsigned short* __restrict__ KTg,
                                                 const unsigned short* __restrict__ Vg,
                                                 unsigned short* __restrict__ OT) {
    __shared__ __align__(16) unsigned short sm[34176];
    unsigned short* smK = sm;
    unsigned short* smV = sm + 16384;
    unsigned short* smP = sm + 32768;
    float* lsum2 = (float*)(sm + 34048);

    const int bid = blockIdx.x;
    const int xcd = bid & 7, slot = bid >> 3;     // slot in [0,64)
    const int b   = xcd * 2 + (slot & 1);         // 2 batches per XCD (K/V L2-resident)
    const int q0  = (slot >> 1) * 32;             // 32-row q-tile

    const int t = threadIdx.x;
    const int w = t >> 6, lane = t & 63;
    const int qg = w & 1, kg = w >> 1;            // S split: 16-q half x 16-key half
    const int r16 = lane & 15, quad = lane >> 4;
    const int srow = lane >> 2;
    const int sc   = (((lane & 3) ^ ((lane >> 3) & 3))) * 8;
    const int swz  = ((quad ^ (r16 >> 1)) & 3) * 8;

    const unsigned short* Qb = QT  + (size_t)b * NTOK * CH;
    const unsigned short* Kb = KTg + (size_t)b * NTOK * CH;
    const unsigned short* Vb = Vg  + (size_t)b * CH * NTOK;

    // Q fragments: wave owns q-rows q0 + qg*16 + r16 (kg-duplicated)
    bf16x8 qf[16];
    {
        const unsigned short* qrow = Qb + (size_t)(q0 + qg * 16 + r16) * CH + quad * 8;
#pragma unroll
        for (int kc = 0; kc < 16; kc++)
            qf[kc] = *(const bf16x8*)(qrow + kc * 32);
    }

    f32x4 accO[16];   // [qj*8+cj]: O[q = qj*16+quad*4+r][c = w*128 + cj*16 + r16]
#pragma unroll
    for (int j = 0; j < 16; j++) accO[j] = (f32x4){0.f, 0.f, 0.f, 0.f};
    float lsum[4] = {0.f, 0.f, 0.f, 0.f};
    const float scale = 0.044194173824159216f;  // 512^-0.5

    // prologue: stage K(0): 32 chunks (chunk = keygroup*16 + kc); wave stages 8
#pragma unroll
    for (int i = 0; i < 8; i++) {
        const int ch = w * 8 + i, g = ch >> 4, kc = ch & 15;
        async16(Kb + (size_t)(g * 16 + srow) * CH + kc * 32 + sc, smK + ch * 512);
    }
    __syncthreads();

    for (int kt = 0; kt < 32; kt++) {
        // stage V(kt): 32 channel-group chunks [16 c][32 k]; wave stages cg = w*8..w*8+7
        {
            const unsigned short* vbase = Vb + (size_t)kt * 32;
#pragma unroll
            for (int i = 0; i < 8; i++) {
                const int cg = w * 8 + i;
                async16(vbase + (size_t)(cg * 16 + srow) * NTOK + sc, smV + cg * 512);
            }
        }
        // S = Q·K^T : wave computes S[16q(qg)][16 keys (kg)]
        f32x4 accS = (f32x4){0.f, 0.f, 0.f, 0.f};
#pragma unroll
        for (int kc = 0; kc < 16; kc++) {
            bf16x8 kf = *(const bf16x8*)(smK + (kg * 16 + kc) * 512 + r16 * 32 + swz);
            accS = __builtin_amdgcn_mfma_f32_16x16x32_bf16(qf[kc], kf, accS, 0, 0, 0);
        }
        // exp + P write (row = qg*16+quad*4+r, col = kg*16+r16) + lsum partial
#pragma unroll
        for (int r = 0; r < 4; r++) {
            float e = __expf(accS[r] * scale);
            lsum[r] += e;
            smP[(qg * 16 + quad * 4 + r) * PS + kg * 16 + r16] = f2bf(e);
        }
        __syncthreads();   // drains V(kt); P visible; smK free
        // stage K(kt+1)
        if (kt < 31) {
            const unsigned short* kbase = Kb + (size_t)(kt + 1) * 32 * CH;
#pragma unroll
            for (int i = 0; i < 8; i++) {
                const int ch = w * 8 + i, g = ch >> 4, kc = ch & 15;
                async16(kbase + (size_t)(g * 16 + srow) * CH + kc * 32 + sc, smK + ch * 512);
            }
        }
        // P frags: A[m=q(r16)][k=key(quad*8+j)], both 16-row q-subtiles
        bf16x8 pf0 = *(const bf16x8*)(smP + (r16)      * PS + quad * 8);
        bf16x8 pf1 = *(const bf16x8*)(smP + (16 + r16) * PS + quad * 8);
        // PV: wave accumulates O[32 q][channels w*128 .. +127]
#pragma unroll
        for (int cj = 0; cj < 8; cj++) {
            bf16x8 vf = *(const bf16x8*)(smV + (w * 8 + cj) * 512 + r16 * 32 + swz);
            accO[cj]     = __builtin_amdgcn_mfma_f32_16x16x32_bf16(pf0, vf, accO[cj], 0, 0, 0);
            accO[8 + cj] = __builtin_amdgcn_mfma_f32_16x16x32_bf16(pf1, vf, accO[8 + cj], 0, 0, 0);
        }
        __syncthreads();   // drains K(kt+1); smV/smP free
    }

    // publish per-(qg,kg) row-sum partials (reduce across the 16 key-lanes)
#pragma unroll
    for (int r = 0; r < 4; r++) {
        float v = lsum[r];
        v += __shfl_xor(v, 1, 64);
        v += __shfl_xor(v, 2, 64);
        v += __shfl_xor(v, 4, 64);
        v += __shfl_xor(v, 8, 64);
        if (r16 == 0) lsum2[kg * 32 + qg * 16 + quad * 4 + r] = v;
    }
    __syncthreads();
    // normalize + transpose tile [32 q][512 c] (stride 520) into sm[0..16640)
#pragma unroll
    for (int qj = 0; qj < 2; qj++) {
        float iv[4];
#pragma unroll
        for (int r = 0; r < 4; r++) {
            const int row = qj * 16 + quad * 4 + r;
            iv[r] = 1.0f / (lsum2[row] + lsum2[32 + row]);
        }
#pragma unroll
        for (int cj = 0; cj < 8; cj++) {
            f32x4 a = accO[qj * 8 + cj];
#pragma unroll
            for (int r = 0; r < 4; r++)
                sm[(qj * 16 + quad * 4 + r) * 520 + w * 128 + cj * 16 + r16] = f2bf(a[r] * iv[r]);
        }
    }
    __syncthreads();
    unsigned short* dst = OT + (size_t)b * NTOK * CH + (size_t)q0 * CH;
#pragma unroll
    for (int p = 0; p < 16; p++) {
        const int row = (t >> 7) + p * 2;
        const int seg = (t & 127) * 4;
        *(ushort4*)(dst + (size_t)row * CH + seg) = *(const ushort4*)(sm + row * 520 + seg);
    }
}

// ---------------- GEMM4: out = OW·O + ob + x ----------------
__global__ __launch_bounds__(256, 2) void k_gemm_out(const unsigned short* __restrict__ OW,
                                                     const float* __restrict__ ob,
                                                     const unsigned short* __restrict__ OT,
                                                     const float* __restrict__ x,
                                                     float* __restrict__ out) {
    __shared__ __align__(16) unsigned short smem[24576];
    const int b  = blockIdx.z;
    const int m0 = blockIdx.y * 128;
    const int n0 = blockIdx.x * 256;
    f32x4 acc[4][8];
    mfma_core2(OW, CH, OT + (size_t)b * NTOK * CH, CH, CH, m0, n0, smem, acc);
    const int t = threadIdx.x;
    const int w = t >> 6, lane = t & 63;
    const int wm = (w & 1) * 64, wn = (w >> 1) * 128;
    const int r16 = lane & 15, quad = lane >> 4;
#pragma unroll
    for (int i = 0; i < 4; i++) {
        const int o0g = m0 + wm + i * 16 + quad * 4;
#pragma unroll
        for (int j = 0; j < 8; j++) {
            const int col = n0 + wn + j * 16 + r16;
            f32x4 a = acc[i][j];
#pragma unroll
            for (int r = 0; r < 4; r++) {
                size_t idx = (size_t)b * CHW + (size_t)(o0g + r) * NTOK + col;
                out[idx] = a[r] + ob[o0g + r] + x[idx];
            }
        }
    }
}

extern "C" void kernel_launch(void* const* d_in, const int* in_sizes, int n_in,
                              void* d_out, int out_size, void* d_ws, size_t ws_size,
                              hipStream_t stream) {
    const float* x      = (const float*)d_in[0];
    const float* norm_w = (const float*)d_in[1];
    const float* norm_b = (const float*)d_in[2];
    const float* qkv_w  = (const float*)d_in[3];
    const float* qkv_b  = (const float*)d_in[4];
    const float* out_w  = (const float*)d_in[5];
    const float* out_b  = (const float*)d_in[6];
    float* out = (float*)d_out;
    char* wsb  = (char*)d_ws;

    float* stats = (float*)wsb;
    unsigned short* WQ  = (unsigned short*)(wsb + OFF_WQKV);
    unsigned short* OW  = (unsigned short*)(wsb + OFF_OW);
    unsigned short* XNT = (unsigned short*)(wsb + OFF_XNT);
    unsigned short* QT  = (unsigned short*)(wsb + OFF_QT);
    unsigned short* KT  = (unsigned short*)(wsb + OFF_KT);
    unsigned short* V   = (unsigned short*)(wsb + OFF_V);
    unsigned short* OT  = (unsigned short*)(wsb + OFF_OT);

    k_cvt2<<<1024, 256, 0, stream>>>(qkv_w, out_w, WQ, OW, stats);
    k_stats_partial<<<BATCH * 64, 256, 0, stream>>>(x, stats);
    k_xnt<<<dim3(NTOK / 64, CH / 64, BATCH), 256, 0, stream>>>(x, norm_w, norm_b, stats, XNT);
    k_gemm_qkv<<<dim3(NTOK / 256, 3 * CH / 128, BATCH), 256, 0, stream>>>(WQ, qkv_b, XNT, QT, KT, V);
    k_attn<<<512, 256, 0, stream>>>(QT, KT, V, OT);
    k_gemm_out<<<dim3(NTOK / 256, CH / 128, BATCH), 256, 0, stream>>>(OW, out_b, OT, x, out);
}